// Round 11
// baseline (1319.867 us; speedup 1.0000x reference)
//
#include <hip/hip_runtime.h>
#include <math.h>

#define N_NODES 50000
#define N_EDGES 400000
#define LD1 232   // edge L1 input ld (208 -> 224 + 8 pad)
#define LDH 136   // hidden ld (128 + 8)
#define LDN 168   // node L1 input ld (144 -> 160 + 8)
#define N_ETILE 12500
#define N_NTILE 1563

typedef _Float16 half8 __attribute__((ext_vector_type(8)));
typedef float f32x4 __attribute__((ext_vector_type(4)));

// workspace layout (bytes)
#define AGG_OFF 0           // 50000*64 f32
#define XH_OFF  12800000    // 50000*64 f16
#define UH_OFF  19200000    // 64*16 f16
#define WP_OFF  19202048    // packed weights, 200704 f16
#define EW_OFF  19603456    // 400000*64 f16 e-out buffer (51.2 MB)
// packed-weight offsets (f16 elements)
#define O_EW1 0
#define O_EH0 28672
#define O_EH1 45056
#define O_EWO 61440
#define O_AW1 69632
#define O_AH0 98304
#define O_AH1 114688
#define O_AWO 131072
#define O_NW1 139264
#define O_NH0 159744
#define O_NH1 176128
#define O_NWO 192512

__device__ __forceinline__ f32x4 mfma16(half8 a, half8 b, f32x4 c) {
  return __builtin_amdgcn_mfma_f32_16x16x32_f16(a, b, c, 0, 0, 0);
}

__device__ __forceinline__ half8 cvt8(float4 a, float4 b) {
  half8 v;
  v[0] = (_Float16)a.x; v[1] = (_Float16)a.y; v[2] = (_Float16)a.z; v[3] = (_Float16)a.w;
  v[4] = (_Float16)b.x; v[5] = (_Float16)b.y; v[6] = (_Float16)b.z; v[7] = (_Float16)b.w;
  return v;
}

__device__ __forceinline__ half8 zero8() {
  half8 v;
#pragma unroll
  for (int j = 0; j < 8; ++j) v[j] = (_Float16)0.f;
  return v;
}

// ---------------------------------------------------------------------------
// GEMM stage, 8 waves x 16 cols = 128 cols, M=32 rows. B from LDS (wB).
// dst[0:32][w*16 .. +16) = relu(src[0:32][0:NS*32] @ W + b), f16, ld=LDH.
// ---------------------------------------------------------------------------
template<int NS, int LDSRC>
__device__ __forceinline__ void gemmL(const _Float16* __restrict__ src,
                                      _Float16* __restrict__ dst,
                                      const half8* __restrict__ wB,
                                      const float* __restrict__ bias,
                                      int w, int lane) {
  const int r = lane & 15, ch = lane >> 4;
  const int c0 = w * 16;
  f32x4 acc0 = (f32x4){0.f, 0.f, 0.f, 0.f};
  f32x4 acc1 = (f32x4){0.f, 0.f, 0.f, 0.f};
#pragma unroll
  for (int s = 0; s < NS; ++s) {
    half8 B  = wB[(s * 4 + ch) * 128 + c0 + r];
    half8 A0 = *(const half8*)(src + r * LDSRC + s * 32 + ch * 8);
    half8 A1 = *(const half8*)(src + (16 + r) * LDSRC + s * 32 + ch * 8);
    acc0 = mfma16(A0, B, acc0);
    acc1 = mfma16(A1, B, acc1);
  }
  float bb = bias[c0 + r];
#pragma unroll
  for (int q = 0; q < 4; ++q) {
    dst[(ch * 4 + q) * LDH + c0 + r]      = (_Float16)fmaxf(acc0[q] + bb, 0.f);
    dst[(16 + ch * 4 + q) * LDH + c0 + r] = (_Float16)fmaxf(acc1[q] + bb, 0.f);
  }
}

// ---------------------------------------------------------------------------
// Output layer, 16-row slab wh in {0,1}, all 64 cols; + bias + LayerNorm.
// B from global (16KB, L1-cache resident after iter 1).
// Result: acc[t][q] = C[row = wh*16 + ch*4 + q][col = t*16 + r], normalized.
// ---------------------------------------------------------------------------
__device__ __forceinline__ void out16(const _Float16* __restrict__ src,
                                      const half8* __restrict__ wpo,
                                      const float* __restrict__ bo,
                                      const float* __restrict__ g,
                                      const float* __restrict__ bt,
                                      f32x4 acc[4], int wh, int lane) {
  const int r = lane & 15, ch = lane >> 4;
#pragma unroll
  for (int t = 0; t < 4; ++t) acc[t] = (f32x4){0.f, 0.f, 0.f, 0.f};
#pragma unroll
  for (int s = 0; s < 4; ++s) {
    half8 a = *(const half8*)(src + (wh * 16 + r) * LDH + s * 32 + ch * 8);
#pragma unroll
    for (int t = 0; t < 4; ++t)
      acc[t] = mfma16(a, wpo[(s * 4 + ch) * 64 + t * 16 + r], acc[t]);
  }
  float g4[4], b4[4];
#pragma unroll
  for (int t = 0; t < 4; ++t) {
    float bv = bo[t * 16 + r];
#pragma unroll
    for (int q = 0; q < 4; ++q) acc[t][q] += bv;
    g4[t] = g[t * 16 + r]; b4[t] = bt[t * 16 + r];
  }
#pragma unroll
  for (int q = 0; q < 4; ++q) {
    float s1 = 0.f, s2 = 0.f;
#pragma unroll
    for (int t = 0; t < 4; ++t) { float v = acc[t][q]; s1 += v; s2 += v * v; }
#pragma unroll
    for (int mk = 1; mk < 16; mk <<= 1) {
      s1 += __shfl_xor(s1, mk); s2 += __shfl_xor(s2, mk);
    }
    float mu = s1 * (1.f / 64);
    float rs = rsqrtf(s2 * (1.f / 64) - mu * mu + 1e-5f);
#pragma unroll
    for (int t = 0; t < 4; ++t)
      acc[t][q] = (acc[t][q] - mu) * rs * g4[t] + b4[t];
  }
}

// ---------------------------------------------------------------------------
// Persistent path kernel (e or a). 1 block/CU (155136 B LDS), weights for
// L1/h0/h1 LDS-resident, grid-stride over 32-edge tiles.
// ---------------------------------------------------------------------------
struct PathP {
  const float* edge_attr; const int* edge_index; const int* batch;
  const _Float16* x_h; const _Float16* u_h; const _Float16* wp;
  const float *Bin, *Bh, *Bout, *G, *Bt;
  _Float16* eW;
  float* agg;
  int w1_off, h0_off, h1_off, wo_off;
};

template<bool IS_A>
__global__ __launch_bounds__(512, 2) void path_kernel(PathP p) {
  extern __shared__ char smem[];
  half8* wL1 = (half8*)smem;                        // 3584 half8 (57344 B)
  half8* wH0 = (half8*)(smem + 57344);              // 2048 (32768 B)
  half8* wH1 = (half8*)(smem + 90112);              // 2048 (32768 B)
  _Float16* sIn   = (_Float16*)(smem + 122880);     // 32*232 (14848 B)
  _Float16* sPing = (_Float16*)(smem + 137728);     // 32*136 (8704 B)
  _Float16* sPong = (_Float16*)(smem + 146432);     // 32*136 (8704 B)

  const int tid = threadIdx.x, lane = tid & 63, w = tid >> 6;
  const int r = lane & 15, ch = lane >> 4;

  {
    const half8* g1 = (const half8*)(p.wp + p.w1_off);
    const half8* g2 = (const half8*)(p.wp + p.h0_off);
    const half8* g3 = (const half8*)(p.wp + p.h1_off);
    for (int i = tid; i < 3584; i += 512) wL1[i] = g1[i];
    for (int i = tid; i < 2048; i += 512) wH0[i] = g2[i];
    for (int i = tid; i < 2048; i += 512) wH1[i] = g3[i];
  }
  __syncthreads();

  const half8* wpo = (const half8*)(p.wp + p.wo_off);

  for (int tile = blockIdx.x; tile < N_ETILE; tile += gridDim.x) {
    const int e0 = tile * 32;

    // stage neigh = [x[src] | x[tgt] | edge_attr | u[batch[src]] | 0] f16
    for (int idx = tid; idx < 1024; idx += 512) {
      int c = idx & 31, e = idx >> 5;
      if (c >= 28) continue;
      int col = c * 8;
      half8 v;
      if (col < 64) {
        int s = p.edge_index[e0 + e];
        v = *(const half8*)(p.x_h + (size_t)s * 64 + col);
      } else if (col < 128) {
        int t = p.edge_index[N_EDGES + e0 + e];
        v = *(const half8*)(p.x_h + (size_t)t * 64 + col - 64);
      } else if (col < 192) {
        const float* ea = p.edge_attr + (size_t)(e0 + e) * 64 + (col - 128);
        v = cvt8(*(const float4*)ea, *(const float4*)(ea + 4));
      } else if (col < 208) {
        int s = p.edge_index[e0 + e];
        int eb = p.batch[s];
        v = *(const half8*)(p.u_h + eb * 16 + col - 192);
      } else {
        v = zero8();
      }
      *(half8*)(sIn + e * LD1 + col) = v;
    }
    __syncthreads();

    gemmL<7, LD1>(sIn, sPing, wL1, p.Bin, w, lane);        __syncthreads();
    gemmL<4, LDH>(sPing, sPong, wH0, p.Bh, w, lane);       __syncthreads();
    gemmL<4, LDH>(sPong, sPing, wH1, p.Bh + 128, w, lane); __syncthreads();

    if (w < 2) {
      f32x4 acc[4];
      out16(sPing, wpo, p.Bout, p.G, p.Bt, acc, w, lane);
      if (!IS_A) {
#pragma unroll
        for (int q = 0; q < 4; ++q) {
          int row = w * 16 + ch * 4 + q;
          _Float16* d = p.eW + (size_t)(e0 + row) * 64 + r;
#pragma unroll
          for (int t = 0; t < 4; ++t) d[t * 16] = (_Float16)acc[t][q];
        }
      } else {
#pragma unroll
        for (int q = 0; q < 4; ++q) {
          int row = w * 16 + ch * 4 + q;
          int tq = p.edge_index[N_EDGES + e0 + row];
          const _Float16* es = p.eW + (size_t)(e0 + row) * 64 + r;
          float* ap = p.agg + (size_t)tq * 64 + r;
#pragma unroll
          for (int t = 0; t < 4; ++t) {
            float sg = 1.f / (1.f + __expf(-acc[t][q]));
            atomicAdd(ap + t * 16, (float)es[t * 16] * sg);
          }
        }
      }
    }
    __syncthreads();
  }
}

// ---------------------------------------------------------------------------
struct NodePP {
  const float* agg; const _Float16* x_h; const _Float16* u_h;
  const _Float16* wp; const int* batch;
  const float *Bin, *Bh, *Bout, *G, *Bt;
  float* out;
};

__global__ __launch_bounds__(512, 2) void node_kernel(NodePP p) {
  extern __shared__ char smem[];
  half8* wL1 = (half8*)smem;                        // 2560 half8 (40960 B)
  half8* wH0 = (half8*)(smem + 40960);              // 2048
  half8* wH1 = (half8*)(smem + 73728);              // 2048
  _Float16* sIn   = (_Float16*)(smem + 106496);     // 32*168 (10752 B)
  _Float16* sPing = (_Float16*)(smem + 117248);     // 8704
  _Float16* sPong = (_Float16*)(smem + 125952);     // 8704  -> total 134656

  const int tid = threadIdx.x, lane = tid & 63, w = tid >> 6;
  const int r = lane & 15, ch = lane >> 4;

  {
    const half8* g1 = (const half8*)(p.wp + O_NW1);
    const half8* g2 = (const half8*)(p.wp + O_NH0);
    const half8* g3 = (const half8*)(p.wp + O_NH1);
    for (int i = tid; i < 2560; i += 512) wL1[i] = g1[i];
    for (int i = tid; i < 2048; i += 512) wH0[i] = g2[i];
    for (int i = tid; i < 2048; i += 512) wH1[i] = g3[i];
  }
  __syncthreads();

  const half8* wpo = (const half8*)(p.wp + O_NWO);

  for (int tile = blockIdx.x; tile < N_NTILE; tile += gridDim.x) {
    const int n0 = tile * 32;

    for (int idx = tid; idx < 1024; idx += 512) {
      int c = idx & 31, e = idx >> 5;
      if (c >= 20) continue;
      int n = n0 + e, col = c * 8;
      half8 v;
      if (n >= N_NODES || col >= 144) {
        v = zero8();
      } else if (col < 64) {
        v = *(const half8*)(p.x_h + (size_t)n * 64 + col);
      } else if (col < 128) {
        const float* ag = p.agg + (size_t)n * 64 + (col - 64);
        v = cvt8(*(const float4*)ag, *(const float4*)(ag + 4));
      } else {
        v = *(const half8*)(p.u_h + p.batch[n] * 16 + col - 128);
      }
      *(half8*)(sIn + e * LDN + col) = v;
    }
    __syncthreads();

    gemmL<5, LDN>(sIn, sPing, wL1, p.Bin, w, lane);        __syncthreads();
    gemmL<4, LDH>(sPing, sPong, wH0, p.Bh, w, lane);       __syncthreads();
    gemmL<4, LDH>(sPong, sPing, wH1, p.Bh + 128, w, lane); __syncthreads();

    if (w < 2) {
      f32x4 acc[4];
      out16(sPing, wpo, p.Bout, p.G, p.Bt, acc, w, lane);
#pragma unroll
      for (int q = 0; q < 4; ++q) {
        int n = n0 + w * 16 + ch * 4 + q;
        if (n < N_NODES) {
#pragma unroll
          for (int t = 0; t < 4; ++t)
            p.out[(size_t)n * 64 + t * 16 + r] = acc[t][q];
        }
      }
    }
    __syncthreads();
  }
}

// ---------------------------------------------------------------------------
// Per-call pack: fp32 weights -> MFMA-B-fragment-packed fp16; x,u -> fp16.
// wdst[((s*4+c)*N + n)*8 + j] = W[s*32+c*8+j][n]  (0 if k >= Kreal)
// ---------------------------------------------------------------------------
#define GX 112
struct PackP {
  const float* src[12];
  int Kreal[12], Nlog[12], size[12], dstoff[12];
  const float* x; const float* u;
  _Float16* x_h; _Float16* u_h; _Float16* wdst;
};

__global__ void pack_kernel(PackP p) {
  int y = blockIdx.y;
  int idx = blockIdx.x * 256 + threadIdx.x;
  if (y < 12) {
    int sz = p.size[y];
    if (idx >= sz) return;
    int N = 1 << p.Nlog[y];
    int j = idx & 7, t = idx >> 3;
    int n = t & (N - 1);
    int sc = t >> p.Nlog[y];
    int c = sc & 3, s = sc >> 2;
    int k = s * 32 + c * 8 + j;
    p.wdst[p.dstoff[y] + idx] =
        (k < p.Kreal[y]) ? (_Float16)p.src[y][k * N + n] : (_Float16)0.f;
  } else {
    for (int i = idx; i < N_NODES * 64 / 8; i += GX * 256) {
      const float* s = p.x + (size_t)i * 8;
      *(half8*)(p.x_h + (size_t)i * 8) =
          cvt8(*(const float4*)s, *(const float4*)(s + 4));
    }
    for (int i = idx; i < 64 * 16 / 8; i += GX * 256) {
      const float* s = p.u + i * 8;
      *(half8*)(p.u_h + i * 8) =
          cvt8(*(const float4*)s, *(const float4*)(s + 4));
    }
  }
}

// ---------------------------------------------------------------------------
extern "C" void kernel_launch(void* const* d_in, const int* in_sizes, int n_in,
                              void* d_out, int out_size, void* d_ws, size_t ws_size,
                              hipStream_t stream) {
  const float* x = (const float*)d_in[0];
  const float* edge_attr = (const float*)d_in[1];
  const float* u = (const float*)d_in[2];
  const int* edge_index = (const int*)d_in[3];
  const int* batch = (const int*)d_in[4];

  char* ws = (char*)d_ws;
  float* agg = (float*)(ws + AGG_OFF);
  _Float16* x_h = (_Float16*)(ws + XH_OFF);
  _Float16* u_h = (_Float16*)(ws + UH_OFF);
  _Float16* wp = (_Float16*)(ws + WP_OFF);
  _Float16* eW = (_Float16*)(ws + EW_OFF);

  hipMemsetAsync(agg, 0, (size_t)N_NODES * 64 * sizeof(float), stream);

  PackP pk;
  const float* eWh = (const float*)d_in[7];
  const float* aWh = (const float*)d_in[15];
  const float* nWh = (const float*)d_in[23];
  const float* srcs[12] = {
      (const float*)d_in[5], eWh, eWh + 16384, (const float*)d_in[9],
      (const float*)d_in[13], aWh, aWh + 16384, (const float*)d_in[17],
      (const float*)d_in[21], nWh, nWh + 16384, (const float*)d_in[25]};
  const int kr[12] = {208, 128, 128, 128, 208, 128, 128, 128, 144, 128, 128, 128};
  const int nl[12] = {7, 7, 7, 6, 7, 7, 7, 6, 7, 7, 7, 6};
  const int sz[12] = {28672, 16384, 16384, 8192, 28672, 16384, 16384, 8192,
                      20480, 16384, 16384, 8192};
  const int off[12] = {O_EW1, O_EH0, O_EH1, O_EWO, O_AW1, O_AH0, O_AH1, O_AWO,
                       O_NW1, O_NH0, O_NH1, O_NWO};
  for (int i = 0; i < 12; ++i) {
    pk.src[i] = srcs[i]; pk.Kreal[i] = kr[i]; pk.Nlog[i] = nl[i];
    pk.size[i] = sz[i]; pk.dstoff[i] = off[i];
  }
  pk.x = x; pk.u = u; pk.x_h = x_h; pk.u_h = u_h; pk.wdst = wp;
  pack_kernel<<<dim3(GX, 13), 256, 0, stream>>>(pk);

  PathP ep;
  ep.edge_attr = edge_attr; ep.edge_index = edge_index; ep.batch = batch;
  ep.x_h = x_h; ep.u_h = u_h; ep.wp = wp;
  ep.eW = eW; ep.agg = agg;

  // e-path
  ep.Bin = (const float*)d_in[6];  ep.Bh = (const float*)d_in[8];
  ep.Bout = (const float*)d_in[10]; ep.G = (const float*)d_in[11];
  ep.Bt = (const float*)d_in[12];
  ep.w1_off = O_EW1; ep.h0_off = O_EH0; ep.h1_off = O_EH1; ep.wo_off = O_EWO;
  path_kernel<false><<<512, 512, 155136, stream>>>(ep);

  // a-path
  ep.Bin = (const float*)d_in[14]; ep.Bh = (const float*)d_in[16];
  ep.Bout = (const float*)d_in[18]; ep.G = (const float*)d_in[19];
  ep.Bt = (const float*)d_in[20];
  ep.w1_off = O_AW1; ep.h0_off = O_AH0; ep.h1_off = O_AH1; ep.wo_off = O_AWO;
  path_kernel<true><<<512, 512, 155136, stream>>>(ep);

  NodePP np;
  np.agg = agg; np.x_h = x_h; np.u_h = u_h; np.wp = wp; np.batch = batch;
  np.Bin = (const float*)d_in[22]; np.Bh = (const float*)d_in[24];
  np.Bout = (const float*)d_in[26]; np.G = (const float*)d_in[27];
  np.Bt = (const float*)d_in[28];
  np.out = (float*)d_out;
  node_kernel<<<512, 512, 134656, stream>>>(np);
}